// Round 5
// baseline (542.666 us; speedup 1.0000x reference)
//
#include <hip/hip_runtime.h>
#include <stdint.h>

#define M_DIM 8192
#define N_DIM 4096
#define K_DIM 4096
#define NUM_VQ (N_DIM * K_DIM / 8)     // 2,097,152 VQ blocks
#define NUM_X  (M_DIM * K_DIM)         // 33,554,432 x elements
#define VQ_BLOCKS (NUM_VQ / 256)       // 8192
#define CVT_BLOCKS (NUM_X / 8 / 256)   // 16384

#define BK     64                      // K per ring stage
#define DEPTH  2                       // LDS ring stages
#define TILES  (K_DIM / BK)            // 64
#define ROUNDS (TILES / DEPTH)         // 32

#define AS1 __attribute__((address_space(1)))
#define AS3 __attribute__((address_space(3)))

typedef __attribute__((ext_vector_type(4))) float f32x4;
typedef __attribute__((ext_vector_type(8))) short bf16x8;
typedef unsigned short u16;

__device__ inline unsigned short f2bf(float f) {
    union { float f; unsigned int i; } v; v.f = f;
    unsigned int x = v.i;
    return (unsigned short)((x + 0x7FFFu + ((x >> 16) & 1u)) >> 16);  // RNE
}

// ---------------------------------------------------------------------------
// prep_w: VQ decompress + fold scale -> bf16 Ws.
// ---------------------------------------------------------------------------
__global__ void prep_w(const int* __restrict__ labels,
                       const float* __restrict__ centroids,
                       const float* __restrict__ scale,
                       u16* __restrict__ Ws) {
    int lane = threadIdx.x & 63;
    int probe = labels[2 * lane + 1];           // odd words of first 64 pairs
    bool is64 = (__ballot(probe != 0) == 0ull); // all-zero => int64 layout
    int i = blockIdx.x * 256 + threadIdx.x;     // VQ block index
    int lab = is64 ? labels[2 * i] : labels[i];
    int kb = i & 511;                           // k-block within row
    f32x4 c0 = ((const f32x4*)centroids)[2 * lab];
    f32x4 c1 = ((const f32x4*)centroids)[2 * lab + 1];
    f32x4 s0 = ((const f32x4*)scale)[2 * kb];
    f32x4 s1 = ((const f32x4*)scale)[2 * kb + 1];
    bf16x8 o;
#pragma unroll
    for (int j = 0; j < 4; ++j) {
        o[j]     = (short)f2bf(c0[j] * s0[j]);
        o[4 + j] = (short)f2bf(c1[j] * s1[j]);
    }
    ((bf16x8*)Ws)[i] = o;
}

// ---------------------------------------------------------------------------
// prep_x: fp32 x -> bf16 Xb.
// ---------------------------------------------------------------------------
__global__ void prep_x(const float* __restrict__ x, u16* __restrict__ Xb) {
    int i = blockIdx.x * 256 + threadIdx.x;
    f32x4 a = ((const f32x4*)x)[2 * i];
    f32x4 c = ((const f32x4*)x)[2 * i + 1];
    bf16x8 o;
#pragma unroll
    for (int j = 0; j < 4; ++j) { o[j] = (short)f2bf(a[j]); o[4 + j] = (short)f2bf(c[j]); }
    ((bf16x8*)Xb)[i] = o;
}

// ---------------------------------------------------------------------------
// Producer/consumer bf16 GEMM, C = A @ Ws^T + bias (fp32 out).
// R7 = R5 skeleton (PASSED at 317us) + register diet for the 128-reg bucket:
//  - __launch_bounds__(384,4): allocator targets <=128 total regs/wave
//    (VGPR + 64 acc-AGPR unified on gfx950) -> 4 waves/SIMD -> 2 blocks/CU.
//  - two-pass fragment reuse: 8 frags live (not 16); sched_barrier(0)
//    between slice-0 MFMAs and slice-1 loads keeps live ranges disjoint.
//  - setprio(1) around MFMA clusters (wave-priority hint; data-flow safe).
// Sync skeleton UNCHANGED from R5: waves 0-3 consume 64x64 quadrants;
// waves 4,5 each produce one full ring stage (A[128][64]+B[128][64], 32KB);
// ready[s] release-STORE r+1 after per-wave vmcnt(0); consumers acquire-spin,
// done[s] release-add after all stage reads (4 adds/stage/round).
// Swizzle (measured 0 conflicts): logical 16B chunk c of row R at phys
// c ^ (R&7); producer LDS dest linear, source col pre-swizzled (lane-const).
// ---------------------------------------------------------------------------
__global__ __launch_bounds__(384, 4)
void gemm_bias(const u16* __restrict__ A, const u16* __restrict__ B,
               const float* __restrict__ bias, float* __restrict__ C) {
    __shared__ u16 buf[DEPTH * 16384];  // stage: A 8192 u16 (128x64) + B 8192
    __shared__ int ready[DEPTH];
    __shared__ int done[DEPTH];

    const int tid  = threadIdx.x;
    const int wave = tid >> 6;
    const int lane = tid & 63;
    const int bm = blockIdx.y * 128;
    const int bn = blockIdx.x * 128;

    if (tid < DEPTH) done[tid] = 0;
    else if (tid < 2 * DEPTH) ready[tid - DEPTH] = 0;
    __syncthreads();                    // the only barrier in this kernel

    if (wave >= 4) {
        // ---------------- producer: wave owns ring stage s ----------------
        const int s = wave - 4;
        u16* stA = buf + s * 16384;
        u16* stB = stA + 8192;
        // one global_load_lds covers 8 rows x 8 chunks (1KB LDS linear).
        // lane -> (row = j*8 + (lane>>3), phys chunk = lane&7); source
        // chunk = phys ^ (row&7) = (lane&7) ^ (lane>>3): lane-constant.
        const int prow = lane >> 3;                  // 0..7
        const int scol = ((lane & 7) ^ prow) * 8;    // pre-swizzled col
        const u16* baseA = A + (size_t)(bm + prow) * K_DIM + scol;
        const u16* baseB = B + (size_t)(bn + prow) * K_DIM + scol;

        for (int r = 0; r < ROUNDS; ++r) {
            const int kt = r * DEPTH + s;
            while (__hip_atomic_load(&done[s], __ATOMIC_ACQUIRE,
                                     __HIP_MEMORY_SCOPE_WORKGROUP) < 4 * r)
                __builtin_amdgcn_s_sleep(1);
            const u16* gA = baseA + kt * BK;
            const u16* gB = baseB + kt * BK;
#pragma unroll
            for (int j = 0; j < 16; ++j)
                __builtin_amdgcn_global_load_lds(
                    (const AS1 void*)(gA + (size_t)(8 * j) * K_DIM),
                    (AS3 void*)(stA + j * 512), 16, 0, 0);
#pragma unroll
            for (int j = 0; j < 16; ++j)
                __builtin_amdgcn_global_load_lds(
                    (const AS1 void*)(gB + (size_t)(8 * j) * K_DIM),
                    (AS3 void*)(stB + j * 512), 16, 0, 0);
            asm volatile("s_waitcnt vmcnt(0)" ::: "memory");  // own loads only
            __hip_atomic_store(&ready[s], r + 1, __ATOMIC_RELEASE,
                               __HIP_MEMORY_SCOPE_WORKGROUP);
        }
        return;
    }

    // ------------------- consumer: wave quadrant (wm, wn) -------------------
    const int wm = (wave >> 1) * 64;
    const int wn = (wave & 1) * 64;
    const int fm = lane & 15;
    // physical 8-col chunk (u16 offset in a 64-elem row) for kk = 0,1
    const int pc0 = (((lane >> 4)    ) ^ (lane & 7)) * 8;
    const int pc1 = (((lane >> 4) | 4) ^ (lane & 7)) * 8;

    f32x4 acc[4][4];
#pragma unroll
    for (int i = 0; i < 4; ++i)
#pragma unroll
        for (int j = 0; j < 4; ++j)
            acc[i][j] = (f32x4){0.f, 0.f, 0.f, 0.f};

    for (int kt = 0; kt < TILES; ++kt) {
        const int s = kt & (DEPTH - 1);
        const int r = kt >> 1;
        while (__hip_atomic_load(&ready[s], __ATOMIC_ACQUIRE,
                                 __HIP_MEMORY_SCOPE_WORKGROUP) < r + 1)
            __builtin_amdgcn_s_sleep(1);
        const u16* stA = buf + s * 16384;
        const u16* stB = stA + 8192;

        bf16x8 af[4], bfr[4];
        // ---- K-slice 0 ----
#pragma unroll
        for (int i = 0; i < 4; ++i)
            af[i] = *(const bf16x8*)&stA[(wm + i * 16 + fm) * 64 + pc0];
#pragma unroll
        for (int j = 0; j < 4; ++j)
            bfr[j] = *(const bf16x8*)&stB[(wn + j * 16 + fm) * 64 + pc0];

        __builtin_amdgcn_s_setprio(1);
#pragma unroll
        for (int i = 0; i < 4; ++i)
#pragma unroll
            for (int j = 0; j < 4; ++j)
                acc[i][j] = __builtin_amdgcn_mfma_f32_16x16x32_bf16(
                    af[i], bfr[j], acc[i][j], 0, 0, 0);
        __builtin_amdgcn_s_setprio(0);

        // keep slice-1 loads from hoisting above slice-0 MFMAs
        // (caps live fragments at 8 -> stays in the 128-reg bucket)
        __builtin_amdgcn_sched_barrier(0);

        // ---- K-slice 1 (reuse the same fragment registers) ----
#pragma unroll
        for (int i = 0; i < 4; ++i)
            af[i] = *(const bf16x8*)&stA[(wm + i * 16 + fm) * 64 + pc1];
#pragma unroll
        for (int j = 0; j < 4; ++j)
            bfr[j] = *(const bf16x8*)&stB[(wn + j * 16 + fm) * 64 + pc1];

        // all reads of this stage done: unblock the producer
        // (release orders the ds_reads before the flag update)
        if (lane == 0)
            __hip_atomic_fetch_add(&done[s], 1, __ATOMIC_RELEASE,
                                   __HIP_MEMORY_SCOPE_WORKGROUP);

        __builtin_amdgcn_s_setprio(1);
#pragma unroll
        for (int i = 0; i < 4; ++i)
#pragma unroll
            for (int j = 0; j < 4; ++j)
                acc[i][j] = __builtin_amdgcn_mfma_f32_16x16x32_bf16(
                    af[i], bfr[j], acc[i][j], 0, 0, 0);
        __builtin_amdgcn_s_setprio(0);
    }

    float biasv[4];
#pragma unroll
    for (int j = 0; j < 4; ++j)
        biasv[j] = bias[bn + wn + j * 16 + (lane & 15)];

    const int crow0 = bm + wm + (lane >> 4) * 4;
    const int ccol0 = bn + wn + (lane & 15);
#pragma unroll
    for (int i = 0; i < 4; ++i)
#pragma unroll
        for (int r = 0; r < 4; ++r) {
            size_t rowoff = (size_t)(crow0 + i * 16 + r) * N_DIM;
#pragma unroll
            for (int j = 0; j < 4; ++j)
                C[rowoff + ccol0 + j * 16] = acc[i][j][r] + biasv[j];
        }
}

extern "C" void kernel_launch(void* const* d_in, const int* in_sizes, int n_in,
                              void* d_out, int out_size, void* d_ws, size_t ws_size,
                              hipStream_t stream) {
    const float* x         = (const float*)d_in[0];   // [4,2048,4096] fp32
    const float* centroids = (const float*)d_in[1];   // [256,8] fp32
    const int*   labels    = (const int*)d_in[2];     // [2M] int32/64
    const float* scale     = (const float*)d_in[3];   // [4096] fp32
    const float* bias      = (const float*)d_in[4];   // [4096] fp32
    float* out             = (float*)d_out;           // [4,2048,4096] fp32

    u16* Ws = (u16*)d_ws;                              // 32 MB
    u16* Xb = (u16*)((char*)d_ws + (size_t)NUM_VQ * 16); // 64 MB

    prep_w<<<VQ_BLOCKS, 256, 0, stream>>>(labels, centroids, scale, Ws);
    prep_x<<<CVT_BLOCKS, 256, 0, stream>>>(x, Xb);

    dim3 grid(N_DIM / 128, M_DIM / 128);
    gemm_bias<<<grid, 384, 0, stream>>>(Xb, Ws, bias, out);
}

// Round 6
// 464.443 us; speedup vs baseline: 1.1684x; 1.1684x over previous
//
#include <hip/hip_runtime.h>
#include <stdint.h>

#define M_DIM 8192
#define N_DIM 4096
#define K_DIM 4096
#define NUM_VQ (N_DIM * K_DIM / 8)     // 2,097,152 VQ blocks
#define NUM_X  (M_DIM * K_DIM)         // 33,554,432 x elements
#define VQ_BLOCKS (NUM_VQ / 256)       // 8192
#define CVT_BLOCKS (NUM_X / 8 / 256)   // 16384

#define BM 256
#define BN 256
#define BK 64                          // K per tile; 64 K-tiles total

#define AS1 __attribute__((address_space(1)))
#define AS3 __attribute__((address_space(3)))

typedef __attribute__((ext_vector_type(4))) float f32x4;
typedef __attribute__((ext_vector_type(8))) short bf16x8;
typedef unsigned short u16;

__device__ inline unsigned short f2bf(float f) {
    union { float f; unsigned int i; } v; v.f = f;
    unsigned int x = v.i;
    return (unsigned short)((x + 0x7FFFu + ((x >> 16) & 1u)) >> 16);  // RNE
}

// ---------------------------------------------------------------------------
// prep_w: VQ decompress + fold scale -> bf16 Ws.  (unchanged, passed)
// ---------------------------------------------------------------------------
__global__ void prep_w(const int* __restrict__ labels,
                       const float* __restrict__ centroids,
                       const float* __restrict__ scale,
                       u16* __restrict__ Ws) {
    int lane = threadIdx.x & 63;
    int probe = labels[2 * lane + 1];           // odd words of first 64 pairs
    bool is64 = (__ballot(probe != 0) == 0ull); // all-zero => int64 layout
    int i = blockIdx.x * 256 + threadIdx.x;     // VQ block index
    int lab = is64 ? labels[2 * i] : labels[i];
    int kb = i & 511;                           // k-block within row
    f32x4 c0 = ((const f32x4*)centroids)[2 * lab];
    f32x4 c1 = ((const f32x4*)centroids)[2 * lab + 1];
    f32x4 s0 = ((const f32x4*)scale)[2 * kb];
    f32x4 s1 = ((const f32x4*)scale)[2 * kb + 1];
    bf16x8 o;
#pragma unroll
    for (int j = 0; j < 4; ++j) {
        o[j]     = (short)f2bf(c0[j] * s0[j]);
        o[4 + j] = (short)f2bf(c1[j] * s1[j]);
    }
    ((bf16x8*)Ws)[i] = o;
}

// ---------------------------------------------------------------------------
// prep_x: fp32 x -> bf16 Xb.  (unchanged, passed)
// ---------------------------------------------------------------------------
__global__ void prep_x(const float* __restrict__ x, u16* __restrict__ Xb) {
    int i = blockIdx.x * 256 + threadIdx.x;
    f32x4 a = ((const f32x4*)x)[2 * i];
    f32x4 c = ((const f32x4*)x)[2 * i + 1];
    bf16x8 o;
#pragma unroll
    for (int j = 0; j < 4; ++j) { o[j] = (short)f2bf(a[j]); o[4 + j] = (short)f2bf(c[j]); }
    ((bf16x8*)Xb)[i] = o;
}

// ---------------------------------------------------------------------------
// R8: 256x256x64 8-phase GEMM (m201-template port), C = A @ Ws^T + bias.
// 512 thr = 8 waves, all compute AND stage. Wave (w>>2, w&3) owns a 128x64
// C block: acc[8][4] f32x4 (128 AGPR). LDS 128KB: buf[c:2][mat:2][256][64]
// bf16, XOR swizzle chunk^=(row&7) (measured 0 conflicts in R1/R5).
// Per iteration (2 K-tiles: even->buf0, odd->buf1), 8 phases; each phase:
//   frag ds_reads (12 at q==0 else 4); 0-2 half-tile stages (gload_lds x2);
//   s_barrier; lgkmcnt(0); setprio(1); 16 MFMA; setprio(0); [vmcnt(4) at
//   p3/p7]; s_barrier.
// Counted vmcnt(4) BEFORE the p3/p7 end-barrier => every wave verifies its
// own loads (all but newest 4 = next tiles' B halves) landed BEFORE
// signaling; barrier then makes that guarantee cross-wave. Staging runs
// 1.5 K-tiles ahead (tightest read margin = 3 phases, same as m201).
// Stage schedule per iter i (t1=2i+1, t2=2i+2, t3=2i+3):
//   p0: buf1.A0<-t1 | p1: buf1.A1<-t1, buf0.B0<-t2 | p2: buf0.B1<-t2
//   p3: -           | p4: buf0.A0<-t2 | p5: buf0.A1<-t2
//   p6: buf1.B0<-t3 | p7: buf1.B1<-t3
// WAR all cleared by phase-end barriers (reads of a region always complete
// >=1 barrier before its restage). Tail iter (i=31): only t1=63 A stages,
// vmcnt(0) at p3.
// ---------------------------------------------------------------------------
template <int Q>
__device__ __forceinline__ void mfma16(f32x4 (&acc)[8][4], const bf16x8 (&a)[2][2],
                                       const bf16x8 (&b)[4][2]) {
    __builtin_amdgcn_s_setprio(1);
#pragma unroll
    for (int mm = 0; mm < 2; ++mm)
#pragma unroll
        for (int n = 0; n < 4; ++n)
#pragma unroll
            for (int ks = 0; ks < 2; ++ks)
                acc[Q * 2 + mm][n] = __builtin_amdgcn_mfma_f32_16x16x32_bf16(
                    a[mm][ks], b[n][ks], acc[Q * 2 + mm][n], 0, 0, 0);
    __builtin_amdgcn_s_setprio(0);
}

__global__ __launch_bounds__(512, 2)
void gemm_bias(const u16* __restrict__ A, const u16* __restrict__ B,
               const float* __restrict__ bias, float* __restrict__ C) {
    __shared__ u16 buf[65536];   // 128KB: [c:2][mat:2][row:256][col:64]

    const int tid = threadIdx.x;
    const int w   = tid >> 6;
    const int l   = tid & 63;

    // XCD-aware chunked swizzle (512 wgs % 8 == 0 -> bijective)
    const int bid = blockIdx.x;
    const int wg  = (bid & 7) * 64 + (bid >> 3);
    const int bm  = (wg >> 4) * BM;          // 32 M-tiles
    const int bn  = (wg & 15) * BN;          // 16 N-tiles

    // ---- staging addressing: wave w covers rows [w*16, w*16+16) of a half
    const int srow = w * 16 + (l >> 3);                // 0..127 within half
    const int scol = ((l & 7) ^ ((l >> 3) & 7)) * 8;   // pre-swizzled col
    const u16* Ag = A + (size_t)(bm + srow) * K_DIM + scol;
    const u16* Bg = B + (size_t)(bn + srow) * K_DIM + scol;

#define STAGE(c, mat, hh, t) do {                                              \
    const u16* _g = ((mat) ? Bg : Ag) + (size_t)(hh) * 128 * K_DIM +           \
                    (size_t)(t) * BK;                                          \
    u16* _l = buf + (c) * 32768 + (mat) * 16384 + (hh) * 8192 + w * 1024;      \
    __builtin_amdgcn_global_load_lds((const AS1 void*)_g, (AS3 void*)_l,       \
                                     16, 0, 0);                                \
    __builtin_amdgcn_global_load_lds((const AS1 void*)(_g + (size_t)8 * K_DIM),\
                                     (AS3 void*)(_l + 512), 16, 0, 0);         \
} while (0)

    // ---- consumer addressing
    const int wm  = (w >> 2) * 128;
    const int wn  = (w & 3) * 64;
    const int fm  = l & 15;
    const int fm7 = fm & 7;
    const int hi  = l >> 4;

#define LDA_(c, m, ks) (*(const bf16x8*)&buf[(c) * 32768 +                      \
    (wm + (m) * 16 + fm) * 64 + (((hi + 4 * (ks)) ^ fm7) * 8)])
#define LDB_(c, n, ks) (*(const bf16x8*)&buf[(c) * 32768 + 16384 +              \
    (wn + (n) * 16 + fm) * 64 + (((hi + 4 * (ks)) ^ fm7) * 8)])

#define READS(c, q) do {                                                        \
    if ((q) == 0) {                                                             \
        b[0][0] = LDB_(c, 0, 0); b[0][1] = LDB_(c, 0, 1);                       \
        b[1][0] = LDB_(c, 1, 0); b[1][1] = LDB_(c, 1, 1);                       \
        b[2][0] = LDB_(c, 2, 0); b[2][1] = LDB_(c, 2, 1);                       \
        b[3][0] = LDB_(c, 3, 0); b[3][1] = LDB_(c, 3, 1);                       \
    }                                                                           \
    a[0][0] = LDA_(c, (q) * 2, 0);     a[0][1] = LDA_(c, (q) * 2, 1);           \
    a[1][0] = LDA_(c, (q) * 2 + 1, 0); a[1][1] = LDA_(c, (q) * 2 + 1, 1);       \
} while (0)

// phase: reads, stages (in __VA_ARGS__), barrier, lgkm drain, 16 MFMA
#define PH(c, q, ...) do {                                                      \
    READS(c, q);                                                                \
    __VA_ARGS__                                                                 \
    __builtin_amdgcn_s_barrier();                                               \
    asm volatile("s_waitcnt lgkmcnt(0)" ::: "memory");                          \
    __builtin_amdgcn_sched_barrier(0);                                          \
    mfma16<q>(acc, a, b);                                                       \
} while (0)
#define ENDPH       __builtin_amdgcn_s_barrier()
#define ENDPH_VM(N) do {                                                        \
    asm volatile("s_waitcnt vmcnt(" #N ")" ::: "memory");                       \
    __builtin_amdgcn_s_barrier();                                               \
} while (0)

    bf16x8 a[2][2], b[4][2];
    f32x4 acc[8][4];
#pragma unroll
    for (int m = 0; m < 8; ++m)
#pragma unroll
        for (int n = 0; n < 4; ++n)
            acc[m][n] = (f32x4){0.f, 0.f, 0.f, 0.f};

    // ---- prologue: tile0 fully (8 loads), tile1 B halves (4 loads).
    // vmcnt(4) BEFORE the barrier: every wave lands tile0 before signaling.
    STAGE(0, 1, 0, 0); STAGE(0, 1, 1, 0);    // buf0.B <- tile0
    STAGE(0, 0, 0, 0); STAGE(0, 0, 1, 0);    // buf0.A <- tile0
    STAGE(1, 1, 0, 1); STAGE(1, 1, 1, 1);    // buf1.B <- tile1 (may fly)
    asm volatile("s_waitcnt vmcnt(4)" ::: "memory");
    __builtin_amdgcn_s_barrier();

    for (int i = 0; i < 31; ++i) {
        const int t1 = 2 * i + 1, t2 = 2 * i + 2, t3 = 2 * i + 3;
        PH(0, 0, STAGE(1, 0, 0, t1););                     ENDPH;
        PH(0, 1, STAGE(1, 0, 1, t1); STAGE(0, 1, 0, t2);); ENDPH;
        PH(0, 2, STAGE(0, 1, 1, t2););                     ENDPH;
        PH(0, 3, );                                        ENDPH_VM(4);
        PH(1, 0, STAGE(0, 0, 0, t2););                     ENDPH;
        PH(1, 1, STAGE(0, 0, 1, t2););                     ENDPH;
        PH(1, 2, STAGE(1, 1, 0, t3););                     ENDPH;
        PH(1, 3, STAGE(1, 1, 1, t3););                     ENDPH_VM(4);
    }

    // ---- tail iteration (i = 31): consume tiles 62 (buf0) and 63 (buf1)
    PH(0, 0, STAGE(1, 0, 0, 63););  ENDPH;
    PH(0, 1, STAGE(1, 0, 1, 63););  ENDPH;
    PH(0, 2, );                     ENDPH;
    PH(0, 3, );                     ENDPH_VM(0);
    PH(1, 0, );                     ENDPH;
    PH(1, 1, );                     ENDPH;
    PH(1, 2, );                     ENDPH;
    PH(1, 3, );                     // no trailing barrier needed

    // ---- epilogue: C = acc + bias
    float biasv[4];
#pragma unroll
    for (int n = 0; n < 4; ++n)
        biasv[n] = bias[bn + wn + n * 16 + fm];
    const int ccol0 = bn + wn + fm;
#pragma unroll
    for (int m = 0; m < 8; ++m)
#pragma unroll
        for (int r = 0; r < 4; ++r) {
            const size_t rowoff = (size_t)(bm + wm + m * 16 + hi * 4 + r) * N_DIM;
#pragma unroll
            for (int n = 0; n < 4; ++n)
                C[rowoff + ccol0 + n * 16] = acc[m][n][r] + biasv[n];
        }
}

extern "C" void kernel_launch(void* const* d_in, const int* in_sizes, int n_in,
                              void* d_out, int out_size, void* d_ws, size_t ws_size,
                              hipStream_t stream) {
    const float* x         = (const float*)d_in[0];   // [4,2048,4096] fp32
    const float* centroids = (const float*)d_in[1];   // [256,8] fp32
    const int*   labels    = (const int*)d_in[2];     // [2M] int32/64
    const float* scale     = (const float*)d_in[3];   // [4096] fp32
    const float* bias      = (const float*)d_in[4];   // [4096] fp32
    float* out             = (float*)d_out;           // [4,2048,4096] fp32

    u16* Ws = (u16*)d_ws;                              // 32 MB
    u16* Xb = (u16*)((char*)d_ws + (size_t)NUM_VQ * 16); // 64 MB

    prep_w<<<VQ_BLOCKS, 256, 0, stream>>>(labels, centroids, scale, Ws);
    prep_x<<<CVT_BLOCKS, 256, 0, stream>>>(x, Xb);

    dim3 grid((M_DIM / BM) * (N_DIM / BN));            // 32*16 = 512
    gemm_bias<<<grid, 512, 0, stream>>>(Xb, Ws, bias, out);
}